// Round 6
// baseline (2339.710 us; speedup 1.0000x reference)
//
#include <hip/hip_runtime.h>
#include <math.h>
#include <limits.h>

#define HH 1280
#define WW 1920
#define OUT_H 427
#define OUT_W 640
#define SENT 0x7fffffff

// ---------------- shared JFA helpers (bit-exact semantics) ----------------
__device__ __forceinline__ int d2f(int pi, int pj, int s) {
    int dr = pi - (s >> 11);
    int dc = pj - (s & 2047);
    return dr * dr + dc * dc;
}
// sequential semantics: take cand iff cand!=SENT and d(cand) < d(cur), strict
__device__ __forceinline__ int pick(int pi, int pj, int cur, int cand) {
    if (cand != SENT) {
        int dn = d2f(pi, pj, cand);
        int dc_ = (cur == SENT) ? INT_MAX : d2f(pi, pj, cur);
        if (dn < dc_) return cand;
    }
    return cur;
}

// ---------------- scatter: project points, atomicAdd depth ----------------
// Reproduces XLA CPU dot lowering bit-exactly: plain mul/add (no FMA),
// ascending-k accumulation, translation added after.
__global__ void scatter_k(const float* __restrict__ pts,
                          const float* __restrict__ pose,
                          const float* __restrict__ extr,
                          const float* __restrict__ intr,
                          float* __restrict__ depth, int N) {
    #pragma clang fp contract(off)
    int t = blockIdx.x * blockDim.x + threadIdx.x;
    int b = blockIdx.y;
    if (t >= N) return;
    const float* p = pts + ((long)b * N + t) * 3;
    float x = p[0], y = p[1], z = p[2];
    const float* P = pose + b * 16;
    const float* E = extr + b * 16;
    const float* K = intr + b * 9;
    float wx = ((x*P[0] + y*P[1]) + z*P[2]) + P[3];
    float wy = ((x*P[4] + y*P[5]) + z*P[6]) + P[7];
    float wz = ((x*P[8] + y*P[9]) + z*P[10]) + P[11];
    float cx = ((wx*E[0] + wy*E[1]) + wz*E[2]) + E[3];
    float cy = ((wx*E[4] + wy*E[5]) + wz*E[6]) + E[7];
    float cz = ((wx*E[8] + wy*E[9]) + wz*E[10]) + E[11];
    float px = (cx*K[0] + cy*K[1]) + cz*K[2];
    float py = (cx*K[3] + cy*K[4]) + cz*K[5];
    float pz = (cx*K[6] + cy*K[7]) + cz*K[8];
    float u = px / pz, v = py / pz;
    int r = (int)floorf(v), c = (int)floorf(u);
    if (r >= 0 && r < HH && c >= 0 && c < WW) {
        float dv = sqrtf((x*x + y*y) + z*z);
        atomicAdd(depth + ((long)b * HH + r) * WW + c, dv);
    }
}

// ---------------- init nearest: self if valid else sentinel (x4 vectorized) ----
__global__ __launch_bounds__(256)
void init_k(const float* __restrict__ depth, int* __restrict__ nr) {
    int jt = blockIdx.x * blockDim.x + threadIdx.x;
    if (jt >= WW / 4) return;
    int j0 = jt * 4;
    int i = blockIdx.y, b = blockIdx.z;
    long t = ((long)b * HH + i) * WW + j0;
    float4 d = *reinterpret_cast<const float4*>(depth + t);
    int4 v;
    v.x = (d.x != 0.0f) ? ((i << 11) | (j0    )) : SENT;
    v.y = (d.y != 0.0f) ? ((i << 11) | (j0 + 1)) : SENT;
    v.z = (d.z != 0.0f) ? ((i << 11) | (j0 + 2)) : SENT;
    v.w = (d.w != 0.0f) ? ((i << 11) | (j0 + 3)) : SENT;
    *reinterpret_cast<int4*>(nr + t) = v;
}

// ---------------- fully-fused one-k-step JFA (all 8 passes, one store) ---------
// Exact recompute-tree of the sequential pass order:
//   P1(-k,-k) P2(-k,0) P3(-k,+k) P4(0,-k) P5(0,+k) P6(+k,-k) P7(+k,0) P8(+k,+k)
// cand of pass (dy,dx) at p sits at p-(dy,dx). All positions are p+(a,b)*k,
// a,b in -3..+3 (grid index 0..6). Mn = per-level needed-slot masks (bit c of
// Mn[a] = offset col c-3 needed at offset row a-3), verified Mn superset chain.
#define PSTEP(SRC, DST, MSRC, MDST, DA, DB)                                     \
    _Pragma("unroll")                                                           \
    for (int a = 0; a < 7; ++a) {                                               \
        _Pragma("unroll")                                                       \
        for (int c = 0; c < 7; ++c) {                                           \
            if (MDST[a] >> c & 1) {                                             \
                int a2 = a + (DA), c2 = c + (DB);                               \
                int cnd = SENT;                                                 \
                if (a2 >= 0 && a2 < 7 && c2 >= 0 && c2 < 7 &&                   \
                    (MSRC[a2] >> c2 & 1) && rv[a2] && cv[c2])                   \
                    cnd = SRC[a2][c2];                                          \
                DST[a][c] = (rv[a] && cv[c])                                    \
                          ? pick(rowc[a], colc[c], SRC[a][c], cnd) : SENT;      \
            }                                                                   \
        }                                                                       \
    }

__global__ __launch_bounds__(192)
void fused8_k(const int* __restrict__ in, int* __restrict__ out, int k) {
    int j = blockIdx.x * 192 + threadIdx.x;
    int i = blockIdx.y, b = blockIdx.z;
    const int* im = in + (long)b * HH * WW;
    int rowc[7], colc[7];
    bool rv[7], cv[7];
    #pragma unroll
    for (int a = 0; a < 7; ++a) {
        rowc[a] = i + (a - 3) * k;
        rv[a] = (unsigned)rowc[a] < (unsigned)HH;
        colc[a] = j + (a - 3) * k;
        cv[a] = (unsigned)colc[a] < (unsigned)WW;
    }
    constexpr unsigned char M0[7] = {0x1C,0x3E,0x7F,0x7F,0x7F,0x3E,0x1C};
    constexpr unsigned char M1[7] = {0x1C,0x3E,0x3F,0x3F,0x1F,0x0E,0x00};
    constexpr unsigned char M2[7] = {0x1C,0x3E,0x3F,0x1F,0x0E,0x00,0x00};
    constexpr unsigned char M3[7] = {0x1C,0x3E,0x3E,0x1C,0x00,0x00,0x00};
    constexpr unsigned char M4[7] = {0x0C,0x1E,0x1E,0x0C,0x00,0x00,0x00};
    constexpr unsigned char M5[7] = {0x08,0x1C,0x1C,0x08,0x00,0x00,0x00};
    constexpr unsigned char M6[7] = {0x00,0x04,0x0C,0x08,0x00,0x00,0x00};
    constexpr unsigned char M7[7] = {0x00,0x00,0x04,0x08,0x00,0x00,0x00};
    constexpr unsigned char M8[7] = {0x00,0x00,0x00,0x08,0x00,0x00,0x00};
    int va[7][7], vb[7][7];
    // L0 loads
    #pragma unroll
    for (int a = 0; a < 7; ++a) {
        #pragma unroll
        for (int c = 0; c < 7; ++c) {
            if (M0[a] >> c & 1)
                va[a][c] = (rv[a] && cv[c]) ? im[(long)rowc[a] * WW + colc[c]]
                                            : SENT;
        }
    }
    PSTEP(va, vb, M0, M1,  1,  1)   // P1 (-k,-k): cand at u+(1,1)
    PSTEP(vb, va, M1, M2,  1,  0)   // P2 (-k, 0)
    PSTEP(va, vb, M2, M3,  1, -1)   // P3 (-k,+k)
    PSTEP(vb, va, M3, M4,  0,  1)   // P4 ( 0,-k)
    PSTEP(va, vb, M4, M5,  0, -1)   // P5 ( 0,+k)
    PSTEP(vb, va, M5, M6, -1,  1)   // P6 (+k,-k)
    PSTEP(va, vb, M6, M7, -1,  0)   // P7 (+k, 0)
    PSTEP(vb, va, M7, M8, -1, -1)   // P8 (+k,+k)
    out[(long)b * HH * WW + (long)i * WW + j] = va[3][3];
}

// ------- fused compose + horizontal resize: one block per image row -------
__global__ __launch_bounds__(256)
void hresize_k(const float* __restrict__ depth,
               const int* __restrict__ nr,
               float* __restrict__ tmp) {
    __shared__ float fbuf[WW];
    __shared__ float dbuf[WW];
    int i = blockIdx.x, b = blockIdx.y;
    const float* dep = depth + (long)b * HH * WW;
    const float* drow = dep + (long)i * WW;
    const int* nrow = nr + ((long)b * HH + i) * WW;
    for (int j = threadIdx.x; j < WW; j += 256) {
        float dv = drow[j];
        float f, dist;
        if (dv != 0.0f) { f = dv; dist = 0.0f; }
        else {
            int nn = nrow[j];
            int rr, cc;
            if (nn == SENT) { rr = HH - 1; cc = WW - 1; }  // clip(BIG) path
            else { rr = nn >> 11; cc = nn & 2047; }
            f = dep[(long)rr * WW + cc];
            float drr = (float)i - (float)rr, dcc = (float)j - (float)cc;
            dist = sqrtf(drr * drr + dcc * dcc);
        }
        fbuf[j] = f; dbuf[j] = dist;
    }
    __syncthreads();
    const float inv = 3.0f;  // 1920/640
    for (int ow = threadIdx.x; ow < OUT_W; ow += 256) {
        float sf = (ow + 0.5f) * inv - 0.5f;
        int i0 = (int)ceilf(sf - inv);
        float a0 = 0.f, a1 = 0.f, wsum = 0.f;
        for (int k = 0; k < 7; ++k) {
            int iw = i0 + k;
            if (iw < 0 || iw >= WW) continue;
            float wgt = 1.0f - fabsf(sf - (float)iw) / inv;
            if (wgt <= 0.0f) continue;
            a0 += wgt * fbuf[iw]; a1 += wgt * dbuf[iw]; wsum += wgt;
        }
        long o = (((long)b * 2 + 0) * HH + i) * OUT_W + ow;
        tmp[o] = a0 / wsum;
        tmp[o + (long)HH * OUT_W] = a1 / wsum;
    }
}

// ---------------- vertical resize (H 1280->427) ----------------
__global__ void vresize_k(const float* __restrict__ tmp, float* __restrict__ out) {
    int ow = blockIdx.x * blockDim.x + threadIdx.x;
    int oh = blockIdx.y, bc = blockIdx.z;  // bc = b*2 + ch
    if (ow >= OUT_W) return;
    const float inv = (float)(1280.0 / 427.0);
    float sf = (oh + 0.5f) * inv - 0.5f;
    int i0 = (int)ceilf(sf - inv);
    float acc = 0.f, wsum = 0.f;
    const float* src = tmp + (long)bc * HH * OUT_W;
    for (int k = 0; k < 7; ++k) {
        int ih = i0 + k;
        if (ih < 0 || ih >= HH) continue;
        float wgt = 1.0f - fabsf(sf - (float)ih) / inv;
        if (wgt <= 0.0f) continue;
        acc += wgt * src[(long)ih * OUT_W + ow];
        wsum += wgt;
    }
    out[((long)bc * OUT_H + oh) * OUT_W + ow] = acc / wsum;
}

extern "C" void kernel_launch(void* const* d_in, const int* in_sizes, int n_in,
                              void* d_out, int out_size, void* d_ws, size_t ws_size,
                              hipStream_t stream) {
    const float* pts  = (const float*)d_in[0];
    const float* pose = (const float*)d_in[1];
    const float* extr = (const float*)d_in[2];
    const float* intr = (const float*)d_in[3];
    int B = in_sizes[1] / 16;
    int N = in_sizes[0] / (3 * B);

    char* ws = (char*)d_ws;
    size_t imgSz = (size_t)B * HH * WW;
    float* depth = (float*)ws;                  // B*H*W f32
    int*   nearA = (int*)(ws + imgSz * 4);      // B*H*W i32
    int*   nearB = (int*)(ws + imgSz * 8);      // B*H*W i32
    float* tmp   = (float*)(ws + imgSz * 12);   // B*2*H*OUT_W f32

    hipMemsetAsync(depth, 0, imgSz * sizeof(float), stream);

    dim3 bs(256);
    scatter_k<<<dim3((N + 255) / 256, B), bs, 0, stream>>>(pts, pose, extr, intr, depth, N);

    init_k<<<dim3((WW / 4 + 255) / 256, HH, B), bs, 0, stream>>>(depth, nearA);

    // full 1+JFA schedule, one dispatch per k-step (8 passes fused, exact)
    const int steps[12] = {1, 1024, 512, 256, 128, 64, 32, 16, 8, 4, 2, 1};
    dim3 gf(WW / 192, HH, B);   // 10 x 1280 x B
    int* cur = nearA; int* nxt = nearB;
    for (int s = 0; s < 12; ++s) {
        fused8_k<<<gf, dim3(192), 0, stream>>>(cur, nxt, steps[s]);
        int* t2 = cur; cur = nxt; nxt = t2;
    }

    hresize_k<<<dim3(HH, B), bs, 0, stream>>>(depth, cur, tmp);
    vresize_k<<<dim3((OUT_W + 255) / 256, OUT_H, B * 2), bs, 0, stream>>>(tmp, (float*)d_out);
}

// Round 7
// 755.375 us; speedup vs baseline: 3.0974x; 3.0974x over previous
//
#include <hip/hip_runtime.h>
#include <math.h>
#include <limits.h>

#define HH 1280
#define WW 1920
#define OUT_H 427
#define OUT_W 640
#define SENT 0x7fffffff

// ---------------- shared JFA helpers (bit-exact semantics) ----------------
__device__ __forceinline__ int d2f(int pi, int pj, int s) {
    int dr = pi - (s >> 11);
    int dc = pj - (s & 2047);
    return dr * dr + dc * dc;
}
// sequential semantics: take cand iff cand!=SENT and d(cand) < d(cur), strict
__device__ __forceinline__ int pick(int pi, int pj, int cur, int cand) {
    if (cand != SENT) {
        int dn = d2f(pi, pj, cand);
        int dc_ = (cur == SENT) ? INT_MAX : d2f(pi, pj, cur);
        if (dn < dc_) return cand;
    }
    return cur;
}

// ---------------- scatter: project points, atomicAdd depth ----------------
// Reproduces XLA CPU dot lowering bit-exactly: plain mul/add (no FMA),
// ascending-k accumulation, translation added after.
__global__ void scatter_k(const float* __restrict__ pts,
                          const float* __restrict__ pose,
                          const float* __restrict__ extr,
                          const float* __restrict__ intr,
                          float* __restrict__ depth, int N) {
    #pragma clang fp contract(off)
    int t = blockIdx.x * blockDim.x + threadIdx.x;
    int b = blockIdx.y;
    if (t >= N) return;
    const float* p = pts + ((long)b * N + t) * 3;
    float x = p[0], y = p[1], z = p[2];
    const float* P = pose + b * 16;
    const float* E = extr + b * 16;
    const float* K = intr + b * 9;
    float wx = ((x*P[0] + y*P[1]) + z*P[2]) + P[3];
    float wy = ((x*P[4] + y*P[5]) + z*P[6]) + P[7];
    float wz = ((x*P[8] + y*P[9]) + z*P[10]) + P[11];
    float cx = ((wx*E[0] + wy*E[1]) + wz*E[2]) + E[3];
    float cy = ((wx*E[4] + wy*E[5]) + wz*E[6]) + E[7];
    float cz = ((wx*E[8] + wy*E[9]) + wz*E[10]) + E[11];
    float px = (cx*K[0] + cy*K[1]) + cz*K[2];
    float py = (cx*K[3] + cy*K[4]) + cz*K[5];
    float pz = (cx*K[6] + cy*K[7]) + cz*K[8];
    float u = px / pz, v = py / pz;
    int r = (int)floorf(v), c = (int)floorf(u);
    if (r >= 0 && r < HH && c >= 0 && c < WW) {
        float dv = sqrtf((x*x + y*y) + z*z);
        atomicAdd(depth + ((long)b * HH + r) * WW + c, dv);
    }
}

// ======== row-LDS staged JFA groups (one block per image row) ========
// 3-pass group, fixed dy: (dy,-k),(dy,0),(dy,+k) in reference order.
// Template FIRST: stage rows from the depth canvas (fused init) instead of
// the nearest map. Guard structure identical to the verified jfa3_k.
template <bool FIRST>
__global__ __launch_bounds__(512)
void jfa3r_k(const void* __restrict__ inv_, int* __restrict__ out, int dy, int k) {
    __shared__ int rows[4][WW];
    int i = blockIdx.x, b = blockIdx.y;
    // stage rows i - t*dy, t=0..3 (out-of-image rows -> SENT)
    if (FIRST) {
        const float* dep = (const float*)inv_ + (long)b * HH * WW;
        #pragma unroll
        for (int t = 0; t < 4; ++t) {
            int r = i - t * dy;
            if (r >= 0 && r < HH) {
                const float4* src = reinterpret_cast<const float4*>(dep + (long)r * WW);
                for (int c4 = threadIdx.x; c4 < WW / 4; c4 += 512) {
                    float4 d = src[c4];
                    int4 v;
                    int c0 = c4 * 4, pb = (r << 11);
                    v.x = (d.x != 0.0f) ? (pb | c0)       : SENT;
                    v.y = (d.y != 0.0f) ? (pb | (c0 + 1)) : SENT;
                    v.z = (d.z != 0.0f) ? (pb | (c0 + 2)) : SENT;
                    v.w = (d.w != 0.0f) ? (pb | (c0 + 3)) : SENT;
                    reinterpret_cast<int4*>(rows[t])[c4] = v;
                }
            } else {
                int4 sv; sv.x = sv.y = sv.z = sv.w = SENT;
                for (int c4 = threadIdx.x; c4 < WW / 4; c4 += 512)
                    reinterpret_cast<int4*>(rows[t])[c4] = sv;
            }
        }
    } else {
        const int* im = (const int*)inv_ + (long)b * HH * WW;
        #pragma unroll
        for (int t = 0; t < 4; ++t) {
            int r = i - t * dy;
            if (r >= 0 && r < HH) {
                const int4* src = reinterpret_cast<const int4*>(im + (long)r * WW);
                for (int c4 = threadIdx.x; c4 < WW / 4; c4 += 512)
                    reinterpret_cast<int4*>(rows[t])[c4] = src[c4];
            } else {
                int4 sv; sv.x = sv.y = sv.z = sv.w = SENT;
                for (int c4 = threadIdx.x; c4 < WW / 4; c4 += 512)
                    reinterpret_cast<int4*>(rows[t])[c4] = sv;
            }
        }
    }
    __syncthreads();
    bool rv1 = (unsigned)(i - dy)     < (unsigned)HH;
    bool rv2 = (unsigned)(i - 2 * dy) < (unsigned)HH;
    int* orow = out + ((long)b * HH + i) * WW;
    for (int j = threadIdx.x; j < WW; j += 512) {
        int r1_pk = ((unsigned)(j + k) < (unsigned)WW) ? rows[1][j + k] : SENT;
        int o1_p = pick(i, j, rows[0][j], r1_pk);
        int o1_m;
        if (rv1) {
            int r2_pk = ((unsigned)(j + k) < (unsigned)WW) ? rows[2][j + k] : SENT;
            o1_m = pick(i - dy, j, rows[1][j], r2_pk);
        } else o1_m = SENT;
        int o2_p = pick(i, j, o1_p, o1_m);
        int o2_q;
        int qj = j - k;
        if (!rv1 || qj < 0) o2_q = SENT;   // q=(i-dy, j-k) outside image
        else {
            int a0 = pick(i - dy, qj, rows[1][qj], rows[2][j]);
            int a1 = rv2 ? pick(i - 2 * dy, qj, rows[2][qj], rows[3][j]) : SENT;
            o2_q = pick(i - dy, qj, a0, a1);
        }
        orow[j] = pick(i, j, o2_p, o2_q);
    }
}

// 2-pass group dy=0: (0,-k),(0,+k) in reference order; row-local.
__global__ __launch_bounds__(512)
void jfa2r_k(const int* __restrict__ in, int* __restrict__ out, int k) {
    __shared__ int row[WW];
    int i = blockIdx.x, b = blockIdx.y;
    const int4* src = reinterpret_cast<const int4*>(in + ((long)b * HH + i) * WW);
    for (int c4 = threadIdx.x; c4 < WW / 4; c4 += 512)
        reinterpret_cast<int4*>(row)[c4] = src[c4];
    __syncthreads();
    int* orow = out + ((long)b * HH + i) * WW;
    for (int j = threadIdx.x; j < WW; j += 512) {
        int a = row[j];
        int apk = ((unsigned)(j + k) < (unsigned)WW) ? row[j + k] : SENT;
        int o1_p = pick(i, j, a, apk);
        int o1_m = (j - k >= 0) ? pick(i, j - k, row[j - k], a) : SENT;
        orow[j] = pick(i, j, o1_p, o1_m);
    }
}

// ------- fused compose + horizontal resize: one block per image row -------
__global__ __launch_bounds__(256)
void hresize_k(const float* __restrict__ depth,
               const int* __restrict__ nr,
               float* __restrict__ tmp) {
    __shared__ float fbuf[WW];
    __shared__ float dbuf[WW];
    int i = blockIdx.x, b = blockIdx.y;
    const float* dep = depth + (long)b * HH * WW;
    const float* drow = dep + (long)i * WW;
    const int* nrow = nr + ((long)b * HH + i) * WW;
    for (int j = threadIdx.x; j < WW; j += 256) {
        float dv = drow[j];
        float f, dist;
        if (dv != 0.0f) { f = dv; dist = 0.0f; }
        else {
            int nn = nrow[j];
            int rr, cc;
            if (nn == SENT) { rr = HH - 1; cc = WW - 1; }  // clip(BIG) path
            else { rr = nn >> 11; cc = nn & 2047; }
            f = dep[(long)rr * WW + cc];
            float drr = (float)i - (float)rr, dcc = (float)j - (float)cc;
            dist = sqrtf(drr * drr + dcc * dcc);
        }
        fbuf[j] = f; dbuf[j] = dist;
    }
    __syncthreads();
    const float inv = 3.0f;  // 1920/640
    for (int ow = threadIdx.x; ow < OUT_W; ow += 256) {
        float sf = (ow + 0.5f) * inv - 0.5f;
        int i0 = (int)ceilf(sf - inv);
        float a0 = 0.f, a1 = 0.f, wsum = 0.f;
        for (int k = 0; k < 7; ++k) {
            int iw = i0 + k;
            if (iw < 0 || iw >= WW) continue;
            float wgt = 1.0f - fabsf(sf - (float)iw) / inv;
            if (wgt <= 0.0f) continue;
            a0 += wgt * fbuf[iw]; a1 += wgt * dbuf[iw]; wsum += wgt;
        }
        long o = (((long)b * 2 + 0) * HH + i) * OUT_W + ow;
        tmp[o] = a0 / wsum;
        tmp[o + (long)HH * OUT_W] = a1 / wsum;
    }
}

// ---------------- vertical resize (H 1280->427) ----------------
__global__ void vresize_k(const float* __restrict__ tmp, float* __restrict__ out) {
    int ow = blockIdx.x * blockDim.x + threadIdx.x;
    int oh = blockIdx.y, bc = blockIdx.z;  // bc = b*2 + ch
    if (ow >= OUT_W) return;
    const float inv = (float)(1280.0 / 427.0);
    float sf = (oh + 0.5f) * inv - 0.5f;
    int i0 = (int)ceilf(sf - inv);
    float acc = 0.f, wsum = 0.f;
    const float* src = tmp + (long)bc * HH * OUT_W;
    for (int k = 0; k < 7; ++k) {
        int ih = i0 + k;
        if (ih < 0 || ih >= HH) continue;
        float wgt = 1.0f - fabsf(sf - (float)ih) / inv;
        if (wgt <= 0.0f) continue;
        acc += wgt * src[(long)ih * OUT_W + ow];
        wsum += wgt;
    }
    out[((long)bc * OUT_H + oh) * OUT_W + ow] = acc / wsum;
}

extern "C" void kernel_launch(void* const* d_in, const int* in_sizes, int n_in,
                              void* d_out, int out_size, void* d_ws, size_t ws_size,
                              hipStream_t stream) {
    const float* pts  = (const float*)d_in[0];
    const float* pose = (const float*)d_in[1];
    const float* extr = (const float*)d_in[2];
    const float* intr = (const float*)d_in[3];
    int B = in_sizes[1] / 16;
    int N = in_sizes[0] / (3 * B);

    char* ws = (char*)d_ws;
    size_t imgSz = (size_t)B * HH * WW;
    float* depth = (float*)ws;                  // B*H*W f32
    int*   nearA = (int*)(ws + imgSz * 4);      // B*H*W i32
    int*   nearB = (int*)(ws + imgSz * 8);      // B*H*W i32
    float* tmp   = (float*)(ws + imgSz * 12);   // B*2*H*OUT_W f32

    hipMemsetAsync(depth, 0, imgSz * sizeof(float), stream);

    dim3 bs(256);
    scatter_k<<<dim3((N + 255) / 256, B), bs, 0, stream>>>(pts, pose, extr, intr, depth, N);

    dim3 gr(HH, B);
    int* cur = nearA; int* nxt = nearB;
    // leading k=1 step: init fused into the first 3-pass group
    jfa3r_k<true><<<gr, 512, 0, stream>>>(depth, cur, -1, 1);
    jfa2r_k<<<gr, 512, 0, stream>>>(cur, nxt, 1);
    { int* t2 = cur; cur = nxt; nxt = t2; }
    jfa3r_k<false><<<gr, 512, 0, stream>>>(cur, nxt, +1, 1);
    { int* t2 = cur; cur = nxt; nxt = t2; }

    const int steps_rest[11] = {1024, 512, 256, 128, 64, 32, 16, 8, 4, 2, 1};
    for (int s = 0; s < 11; ++s) {
        int k = steps_rest[s];
        jfa3r_k<false><<<gr, 512, 0, stream>>>(cur, nxt, -k, k);
        { int* t2 = cur; cur = nxt; nxt = t2; }
        jfa2r_k<<<gr, 512, 0, stream>>>(cur, nxt, k);
        { int* t2 = cur; cur = nxt; nxt = t2; }
        jfa3r_k<false><<<gr, 512, 0, stream>>>(cur, nxt, +k, k);
        { int* t2 = cur; cur = nxt; nxt = t2; }
    }

    hresize_k<<<dim3(HH, B), bs, 0, stream>>>(depth, cur, tmp);
    vresize_k<<<dim3((OUT_W + 255) / 256, OUT_H, B * 2), bs, 0, stream>>>(tmp, (float*)d_out);
}